// Round 5
// baseline (204.862 us; speedup 1.0000x reference)
//
#include <hip/hip_runtime.h>

typedef _Float16 f16;
typedef _Float16 f16x8 __attribute__((ext_vector_type(8)));
typedef _Float16 f16x4 __attribute__((ext_vector_type(4)));
typedef __fp16 h2 __attribute__((ext_vector_type(2)));
typedef float f32x4 __attribute__((ext_vector_type(4)));
typedef float f32x16 __attribute__((ext_vector_type(16)));
typedef unsigned u32x2 __attribute__((ext_vector_type(2)));

#define S_LEN 4096
#define B_SZ  4
#define E_DIM 1024
#define D_DIM 64
#define NROWS (B_SZ * S_LEN)                 // 16384
#define NSPLIT 4                             // attention split-K factor
// Q scale: 1/sqrt(64) * log2(e) so softmax can use exp2 (2^(s*log2e) == e^s).
#define QSCALE (0.125f * 1.44269504088896f)
// Fixed softmax shift: 2^(s-C) is an EXACT power-of-2 rescale of e^raw/2^C ->
// softmax ratios unchanged.
#define SMAX 8.0f

__device__ __forceinline__ float exp2g(float x) { return __builtin_amdgcn_exp2f(x); }

// ---------------------------------------------------------------------------
// W pack: Wq,Wk fp32 [64][1024] -> Bp in B-fragment order, f16.
// Bp element id = ((n*32 + kc)*64 + lane)*8 + j  holds W[n*16 + (lane&15)]
// [kc*32 + (lane>>4)*8 + j]  (n 0..7: 0-3 = Wq rows, 4-7 = Wk rows).
// Also zeroes the attn completion counters (runs before attn in-stream).
// ---------------------------------------------------------------------------
__global__ __launch_bounds__(256) void wpack_kernel(const float* __restrict__ Wq,
                                                    const float* __restrict__ Wk,
                                                    f16* __restrict__ Bp,
                                                    unsigned* __restrict__ Cnt) {
    if (blockIdx.x == 0 && threadIdx.x < 128) Cnt[threadIdx.x] = 0;
    int id = blockIdx.x * 256 + threadIdx.x;   // 16384 = 8n * 32kc * 64lane
    int lane = id & 63, kc = (id >> 6) & 31, n = id >> 11;
    int row = n * 16 + (lane & 15);
    int col = kc * 32 + (lane >> 4) * 8;
    const float* src = (row < 64) ? (Wq + (long)row * E_DIM + col)
                                  : (Wk + (long)(row - 64) * E_DIM + col);
    float4 v0 = ((const float4*)src)[0];
    float4 v1 = ((const float4*)src)[1];
    f16x8 h = {(f16)v0.x, (f16)v0.y, (f16)v0.z, (f16)v0.w,
               (f16)v1.x, (f16)v1.y, (f16)v1.z, (f16)v1.w};
    *(f16x8*)(Bp + (long)id * 8) = h;
}

// ---------------------------------------------------------------------------
// Projection: 32 rows/block, n-split (no split-K reduce). Wave w owns output
// col-groups {2w, 2w+1}; full-K in-register accumulation; LDS bounce store.
// ---------------------------------------------------------------------------
__global__ __launch_bounds__(256, 2) void proj_kernel(const float* __restrict__ x,
                                                      const f16* __restrict__ Bp,
                                                      f16* __restrict__ Qh,
                                                      f16* __restrict__ Kh) {
    __shared__ union {
        f16 xs[32][1032];   // 64.5 KB
        f16 os[32][136];    // 8.7 KB out-bounce (xs dead by then)
    } sm;

    const int tid  = threadIdx.x;
    const int w    = tid >> 6;
    const int lane = tid & 63;
    const int l15  = lane & 15;
    const int quad = lane >> 4;
    const long m0  = (long)blockIdx.x * 32;

    // stage 32 rows x 1024 cols fp32 -> f16, coalesced
#pragma unroll
    for (int c = 0; c < 16; c++) {
        int f8 = c * 256 + tid;            // f16x8 slot; 128 per row
        int row = f8 >> 7;
        int col = (f8 & 127) * 8;
        const float* src = x + (m0 + row) * E_DIM + col;
        float4 v0 = ((const float4*)src)[0];
        float4 v1 = ((const float4*)src)[1];
        f16x8 h = {(f16)v0.x, (f16)v0.y, (f16)v0.z, (f16)v0.w,
                   (f16)v1.x, (f16)v1.y, (f16)v1.z, (f16)v1.w};
        *(f16x8*)&sm.xs[row][col] = h;
    }
    __syncthreads();

    f32x4 acc[2][2];                        // [m-tile][nn]
#pragma unroll
    for (int m = 0; m < 2; m++)
#pragma unroll
        for (int nn = 0; nn < 2; nn++) acc[m][nn] = (f32x4){0.f, 0.f, 0.f, 0.f};

    const int n0 = w * 2;
#pragma unroll 4
    for (int kc = 0; kc < 32; kc++) {
        f16x8 a0 = *(const f16x8*)&sm.xs[l15][kc * 32 + quad * 8];
        f16x8 a1 = *(const f16x8*)&sm.xs[16 + l15][kc * 32 + quad * 8];
#pragma unroll
        for (int nn = 0; nn < 2; nn++) {
            f16x8 b = *(const f16x8*)(Bp + (((long)(n0 + nn) * 32 + kc) * 64 + lane) * 8);
            acc[0][nn] = __builtin_amdgcn_mfma_f32_16x16x32_f16(a0, b, acc[0][nn], 0, 0, 0);
            acc[1][nn] = __builtin_amdgcn_mfma_f32_16x16x32_f16(a1, b, acc[1][nn], 0, 0, 0);
        }
    }
    __syncthreads();   // all waves done reading xs before os overwrites it

    // dump f16 results (C layout: row = m*16 + quad*4 + r, col = n*16 + l15)
#pragma unroll
    for (int m = 0; m < 2; m++)
#pragma unroll
        for (int nn = 0; nn < 2; nn++) {
            int colg = w * 32 + nn * 16 + l15;
            float sc = (colg < 64) ? QSCALE : 1.0f;
#pragma unroll
            for (int r = 0; r < 4; r++)
                sm.os[m * 16 + quad * 4 + r][colg] = (f16)(acc[m][nn][r] * sc);
        }
    __syncthreads();

    // coalesced store: thread t -> row t>>3, col-group t&7 (two f16x8)
    {
        int row = tid >> 3, cg = tid & 7;
        long grow = m0 + row;
#pragma unroll
        for (int h = 0; h < 2; h++) {
            int col = cg * 16 + h * 8;
            f16x8 v = *(const f16x8*)&sm.os[row][col];
            if (col < 64) *(f16x8*)(Qh + grow * 64 + col)        = v;
            else          *(f16x8*)(Kh + grow * 64 + (col - 64)) = v;
        }
    }
}

// ---------------------------------------------------------------------------
// Flash attention v5: v3 structure (stride-72 b128 LDS — round-4's b64 split
// was neutral-to-negative, reverted) + FUSED COMBINE: the last of the 4
// split-K blocks per (b,qt) combines partials and writes the final output
// (device-scope fence + atomic counter; saves the combine dispatch + gap).
// 32x32x16 MFMA, swapped QK^T, in-register P via cvt_pkrtz+permlane32_swap,
// fdot2 row-sums, 128-row q-tiles, split-K-4, double-buffered K staging,
// one barrier per 64-row k-tile, balanced (31-q, q) block pairing.
// ---------------------------------------------------------------------------
__global__ __launch_bounds__(256, 2) void attn_kernel(const f16* __restrict__ Qh,
                                                      const f16* __restrict__ Kh,
                                                      float* __restrict__ Out,
                                                      float* __restrict__ OutP0,
                                                      f16* __restrict__ P123,
                                                      float* __restrict__ Ml,
                                                      unsigned* __restrict__ Cnt) {
    __shared__ __align__(16) f16 Kr[2][64][72];   // 18 KB x2 (double-buffered)
    __shared__ __align__(16) f16 Kt[2][64][72];   // K transposed (V side)
    __shared__ int lastFlag;

    const int tid  = threadIdx.x;
    const int w    = tid >> 6;
    const int lane = tid & 63;
    const int l31  = lane & 31;
    const int hi   = lane >> 5;

    const int bid  = blockIdx.x;
    const int b    = bid & 3;
    const int half = (bid >> 2) & 3;
    const int qraw = bid >> 4;                    // 0..31
    const int qt   = (qraw < 16) ? (31 - qraw) : (qraw - 16);
    const int q0i  = qt * 128;
    const long q0  = (long)q0i;
    const int jmax = 2 * qt + 1;                  // last 64-row k-tile index

    const f16* Qb = Qh + (long)b * S_LEN * 64;
    const f16* Kb = Kh + (long)b * S_LEN * 64;

    // Q as QK B-frags: lane (col=q=l31, hi) holds Q[q][kf*16 + hi*8 + j]
    f16x8 Bq[4];
#pragma unroll
    for (int kf = 0; kf < 4; kf++)
        Bq[kf] = *(const f16x8*)(Qb + (q0 + w * 32 + l31) * 64 + kf * 16 + hi * 8);

    f32x16 O0 = {}, O1 = {};
    float Lc[4] = {0.f, 0.f, 0.f, 0.f};

    f16x8 pre[2];
    if (half <= jmax) {
#pragma unroll
        for (int it = 0; it < 2; it++)
            pre[it] = *(const f16x8*)(Kb + ((long)half * 64 + lane) * 64 + (w + it * 4) * 8);
    }

    int buf = 0;
    for (int j = half; j <= jmax; j += NSPLIT) {
        // stage current tile into buf (other buffer may still be read by
        // waves before the barrier -> safe)
#pragma unroll
        for (int it = 0; it < 2; it++) {
            int sg = w + it * 4;
            *(f16x8*)&Kr[buf][lane][sg * 8] = pre[it];
#pragma unroll
            for (int i = 0; i < 8; i++) Kt[buf][sg * 8 + i][lane] = pre[it][i];
        }
        if (j + NSPLIT <= jmax) {
#pragma unroll
            for (int it = 0; it < 2; it++)
                pre[it] = *(const f16x8*)(Kb + ((long)(j + NSPLIT) * 64 + lane) * 64 + (w + it * 4) * 8);
        }
        __syncthreads();   // the ONLY barrier per k-tile

        const int od = j * 64 - q0i;              // k-tile offset rel. q-tile
        const bool alive = (od <= w * 32 + 31);   // any unmasked k for wave?
        if (alive) {
            // ---- QK^T swapped: Sc[kb] = K[kb]*Q^T  (C: row=k, col=q) ----
            f32x16 Sc0 = {}, Sc1 = {};
            __builtin_amdgcn_s_setprio(1);
#pragma unroll
            for (int kf = 0; kf < 4; kf++) {
                f16x8 a0 = *(const f16x8*)&Kr[buf][l31][kf * 16 + hi * 8];
                f16x8 a1 = *(const f16x8*)&Kr[buf][32 + l31][kf * 16 + hi * 8];
                Sc0 = __builtin_amdgcn_mfma_f32_32x32x16_f16(a0, Bq[kf], Sc0, 0, 0, 0);
                Sc1 = __builtin_amdgcn_mfma_f32_32x32x16_f16(a1, Bq[kf], Sc1, 0, 0, 0);
            }
            __builtin_amdgcn_s_setprio(0);

            // causal mask: k_g = od + kb*32 + rc + 4hi  vs  q_g = w*32 + l31
            if (od + 63 > w * 32) {
                const int thr = w * 32 + l31 - od - 4 * hi;
#pragma unroll
                for (int r = 0; r < 16; r++) {
                    const int rc = (r & 3) + 8 * (r >> 2);
                    if (rc > thr)      Sc0[r] = -1e30f;
                    if (rc + 32 > thr) Sc1[r] = -1e30f;
                }
            }

            // ---- fixed-shift softmax numerator, in-register ----
            f32x16 pe0, pe1;
#pragma unroll
            for (int r = 0; r < 16; r++) {
                pe0[r] = exp2g(Sc0[r] - SMAX);
                pe1[r] = exp2g(Sc1[r] - SMAX);
            }

            // pack to f16 pairs: C[u][cp] = pkrtz(pe[u>>2][4(u&3)+2cp], +1)
            unsigned Cw[8][2];
#pragma unroll
            for (int u = 0; u < 8; u++) {
#pragma unroll
                for (int cp = 0; cp < 2; cp++) {
                    const int e = 4 * (u & 3) + 2 * cp;
                    h2 t = (u < 4) ? __builtin_amdgcn_cvt_pkrtz(pe0[e], pe0[e + 1])
                                   : __builtin_amdgcn_cvt_pkrtz(pe1[e], pe1[e + 1]);
                    Cw[u][cp] = __builtin_bit_cast(unsigned, t);
                }
            }

            // row-sum L from the SAME f16-rounded P (consistent with PV)
            h2 one2;
            one2[0] = (__fp16)1.f;
            one2[1] = (__fp16)1.f;
#pragma unroll
            for (int u = 0; u < 8; u++)
#pragma unroll
                for (int cp = 0; cp < 2; cp++) {
                    const int c = (u & 1) * 2 + cp;
                    Lc[c] = __builtin_amdgcn_fdot2(__builtin_bit_cast(h2, Cw[u][cp]),
                                                   one2, Lc[c], false);
                }

            // redistribute into PV A-frags: one swap fills two words
            f16x8 pa[4];
#pragma unroll
            for (int kc = 0; kc < 4; kc++) {
                u32x2 s0 = __builtin_amdgcn_permlane32_swap(Cw[2 * kc][0], Cw[2 * kc + 1][0], false, false);
                u32x2 s1 = __builtin_amdgcn_permlane32_swap(Cw[2 * kc][1], Cw[2 * kc + 1][1], false, false);
                union { unsigned uw[4]; f16x8 v; } pw;
                pw.uw[0] = s0.x; pw.uw[1] = s1.x; pw.uw[2] = s0.y; pw.uw[3] = s1.y;
                pa[kc] = pw.v;
            }

            // ---- PV: O[nb] += P * V  (V = K; B-frag from Kt) ----
            __builtin_amdgcn_s_setprio(1);
#pragma unroll
            for (int kc = 0; kc < 4; kc++) {
                f16x8 v0 = *(const f16x8*)&Kt[buf][l31][kc * 16 + hi * 8];
                f16x8 v1 = *(const f16x8*)&Kt[buf][32 + l31][kc * 16 + hi * 8];
                O0 = __builtin_amdgcn_mfma_f32_32x32x16_f16(pa[kc], v0, O0, 0, 0, 0);
                O1 = __builtin_amdgcn_mfma_f32_32x32x16_f16(pa[kc], v1, O1, 0, 0, 0);
            }
            __builtin_amdgcn_s_setprio(0);
        }
        buf ^= 1;
    }

    // finish L: each lane has half the k's for its q; partner lane^32 has rest
    float Lt = Lc[0] + Lc[1] + Lc[2] + Lc[3];
    Lt += __shfl_xor(Lt, 32, 64);

    // write partials. O C-layout: col = nb*32 + l31, row q = rc + 4hi.
    const long growbase = (long)b * S_LEN + q0;
#pragma unroll
    for (int r = 0; r < 16; r++) {
        const int rc = (r & 3) + 8 * (r >> 2);
        long grow = growbase + w * 32 + rc + 4 * hi;
        if (half == 0) {
            OutP0[grow * 64 + l31]      = O0[r];
            OutP0[grow * 64 + 32 + l31] = O1[r];
        } else {
            f16* dst = P123 + (long)(half - 1) * NROWS * 64;
            dst[grow * 64 + l31]      = (f16)O0[r];
            dst[grow * 64 + 32 + l31] = (f16)O1[r];
        }
    }
    if (hi == 0) Ml[(long)half * NROWS + growbase + w * 32 + l31] = Lt;

    // ---- fused combine: last-arriving split-K block finalizes this q-tile --
    // release: every thread fences its writes, sync, then tid0 does the atomic
    __threadfence();
    __syncthreads();
    if (tid == 0) {
        unsigned old = atomicAdd(&Cnt[b * 32 + qt], 1u);
        lastFlag = (old == 3u);
    }
    __syncthreads();
    if (lastFlag) {
        __threadfence();   // acquire: order reads after observing count==3
        // 128 rows x 16 float4 col-groups = 2048 units, 8 per thread
        for (int i = tid; i < 2048; i += 256) {
            const int row = i >> 4;
            const int c0  = (i & 15) * 4;
            const long grow = growbase + row;
            float lt = 0.f;
#pragma unroll
            for (int h = 0; h < 4; h++) lt += Ml[(long)h * NROWS + grow];
            const float inv = 1.0f / lt;
            float4 res = *(const float4*)(OutP0 + grow * 64 + c0);
#pragma unroll
            for (int h = 1; h < 4; h++) {
                f16x4 oh = *(const f16x4*)(P123 + (long)(h - 1) * NROWS * 64 + grow * 64 + c0);
                res.x += (float)oh[0];
                res.y += (float)oh[1];
                res.z += (float)oh[2];
                res.w += (float)oh[3];
            }
            *(float4*)(Out + grow * 64 + c0) =
                make_float4(res.x * inv, res.y * inv, res.z * inv, res.w * inv);
        }
    }
}

// ---------------------------------------------------------------------------
extern "C" void kernel_launch(void* const* d_in, const int* in_sizes, int n_in,
                              void* d_out, int out_size, void* d_ws, size_t ws_size,
                              hipStream_t stream) {
    const float* x  = (const float*)d_in[0];
    const float* Wq = (const float*)d_in[1];
    const float* Wk = (const float*)d_in[2];
    // d_in[3] (Wv) unused: reference computes V with Wk.
    float* out = (float*)d_out;

    // ws layout (~14.8 MB total)
    f16* Qh      = (f16*)d_ws;                           // 2 MB
    f16* Kh      = Qh + (long)NROWS * D_DIM;             // 2 MB
    f16* Bp      = Kh + (long)NROWS * D_DIM;             // 0.25 MB (packed W frags)
    f16* P123    = Bp + (long)128 * E_DIM;               // 6 MB (3 partials, f16)
    float* Ml    = (float*)(P123 + 3L * NROWS * D_DIM);  // 0.25 MB (4 halves)
    float* OutP0 = Ml + 4L * NROWS;                      // 4 MB (half-0 fp32)
    unsigned* Cnt = (unsigned*)(OutP0 + (long)NROWS * D_DIM); // 512 B

    wpack_kernel<<<dim3(64), dim3(256), 0, stream>>>(Wq, Wk, Bp, Cnt);
    proj_kernel<<<dim3(NROWS / 32), dim3(256), 0, stream>>>(x, Bp, Qh, Kh);
    attn_kernel<<<dim3(32 * NSPLIT * B_SZ), dim3(256), 0, stream>>>(Qh, Kh, out, OutP0, P123, Ml, Cnt);
}

// Round 6
// 124.158 us; speedup vs baseline: 1.6500x; 1.6500x over previous
//
#include <hip/hip_runtime.h>

typedef _Float16 f16;
typedef _Float16 f16x8 __attribute__((ext_vector_type(8)));
typedef _Float16 f16x4 __attribute__((ext_vector_type(4)));
typedef __fp16 h2 __attribute__((ext_vector_type(2)));
typedef float f32x4 __attribute__((ext_vector_type(4)));
typedef float f32x16 __attribute__((ext_vector_type(16)));
typedef unsigned u32x2 __attribute__((ext_vector_type(2)));

#define S_LEN 4096
#define B_SZ  4
#define E_DIM 1024
#define D_DIM 64
#define NROWS (B_SZ * S_LEN)                 // 16384
// split-K 8: grid 1024 -> 4 blocks/CU (2 was the latency-hiding limiter;
// total staging/barrier/compute work is invariant under the split factor)
#define NSPLIT 8
// Q scale: 1/sqrt(64) * log2(e) so softmax can use exp2 (2^(s*log2e) == e^s).
#define QSCALE (0.125f * 1.44269504088896f)
// Fixed softmax shift: 2^(s-C) is an EXACT power-of-2 rescale of e^raw/2^C ->
// softmax ratios unchanged.
#define SMAX 8.0f

__device__ __forceinline__ float exp2g(float x) { return __builtin_amdgcn_exp2f(x); }

// ---------------------------------------------------------------------------
// W pack: Wq,Wk fp32 [64][1024] -> Bp in B-fragment order, f16.
// Bp element id = ((n*32 + kc)*64 + lane)*8 + j  holds W[n*16 + (lane&15)]
// [kc*32 + (lane>>4)*8 + j]  (n 0..7: 0-3 = Wq rows, 4-7 = Wk rows).
// ---------------------------------------------------------------------------
__global__ __launch_bounds__(256) void wpack_kernel(const float* __restrict__ Wq,
                                                    const float* __restrict__ Wk,
                                                    f16* __restrict__ Bp) {
    int id = blockIdx.x * 256 + threadIdx.x;   // 16384 = 8n * 32kc * 64lane
    int lane = id & 63, kc = (id >> 6) & 31, n = id >> 11;
    int row = n * 16 + (lane & 15);
    int col = kc * 32 + (lane >> 4) * 8;
    const float* src = (row < 64) ? (Wq + (long)row * E_DIM + col)
                                  : (Wk + (long)(row - 64) * E_DIM + col);
    float4 v0 = ((const float4*)src)[0];
    float4 v1 = ((const float4*)src)[1];
    f16x8 h = {(f16)v0.x, (f16)v0.y, (f16)v0.z, (f16)v0.w,
               (f16)v1.x, (f16)v1.y, (f16)v1.z, (f16)v1.w};
    *(f16x8*)(Bp + (long)id * 8) = h;
}

// ---------------------------------------------------------------------------
// Projection: 32 rows/block, n-split (no split-K reduce). Wave w owns output
// col-groups {2w, 2w+1}; full-K in-register accumulation; LDS bounce store.
// ---------------------------------------------------------------------------
__global__ __launch_bounds__(256, 2) void proj_kernel(const float* __restrict__ x,
                                                      const f16* __restrict__ Bp,
                                                      f16* __restrict__ Qh,
                                                      f16* __restrict__ Kh) {
    __shared__ union {
        f16 xs[32][1032];   // 64.5 KB
        f16 os[32][136];    // 8.7 KB out-bounce (xs dead by then)
    } sm;

    const int tid  = threadIdx.x;
    const int w    = tid >> 6;
    const int lane = tid & 63;
    const int l15  = lane & 15;
    const int quad = lane >> 4;
    const long m0  = (long)blockIdx.x * 32;

    // stage 32 rows x 1024 cols fp32 -> f16, coalesced
#pragma unroll
    for (int c = 0; c < 16; c++) {
        int f8 = c * 256 + tid;            // f16x8 slot; 128 per row
        int row = f8 >> 7;
        int col = (f8 & 127) * 8;
        const float* src = x + (m0 + row) * E_DIM + col;
        float4 v0 = ((const float4*)src)[0];
        float4 v1 = ((const float4*)src)[1];
        f16x8 h = {(f16)v0.x, (f16)v0.y, (f16)v0.z, (f16)v0.w,
                   (f16)v1.x, (f16)v1.y, (f16)v1.z, (f16)v1.w};
        *(f16x8*)&sm.xs[row][col] = h;
    }
    __syncthreads();

    f32x4 acc[2][2];                        // [m-tile][nn]
#pragma unroll
    for (int m = 0; m < 2; m++)
#pragma unroll
        for (int nn = 0; nn < 2; nn++) acc[m][nn] = (f32x4){0.f, 0.f, 0.f, 0.f};

    const int n0 = w * 2;
#pragma unroll 4
    for (int kc = 0; kc < 32; kc++) {
        f16x8 a0 = *(const f16x8*)&sm.xs[l15][kc * 32 + quad * 8];
        f16x8 a1 = *(const f16x8*)&sm.xs[16 + l15][kc * 32 + quad * 8];
#pragma unroll
        for (int nn = 0; nn < 2; nn++) {
            f16x8 b = *(const f16x8*)(Bp + (((long)(n0 + nn) * 32 + kc) * 64 + lane) * 8);
            acc[0][nn] = __builtin_amdgcn_mfma_f32_16x16x32_f16(a0, b, acc[0][nn], 0, 0, 0);
            acc[1][nn] = __builtin_amdgcn_mfma_f32_16x16x32_f16(a1, b, acc[1][nn], 0, 0, 0);
        }
    }
    __syncthreads();   // all waves done reading xs before os overwrites it

    // dump f16 results (C layout: row = m*16 + quad*4 + r, col = n*16 + l15)
#pragma unroll
    for (int m = 0; m < 2; m++)
#pragma unroll
        for (int nn = 0; nn < 2; nn++) {
            int colg = w * 32 + nn * 16 + l15;
            float sc = (colg < 64) ? QSCALE : 1.0f;
#pragma unroll
            for (int r = 0; r < 4; r++)
                sm.os[m * 16 + quad * 4 + r][colg] = (f16)(acc[m][nn][r] * sc);
        }
    __syncthreads();

    // coalesced store: thread t -> row t>>3, col-group t&7 (two f16x8)
    {
        int row = tid >> 3, cg = tid & 7;
        long grow = m0 + row;
#pragma unroll
        for (int h = 0; h < 2; h++) {
            int col = cg * 16 + h * 8;
            f16x8 v = *(const f16x8*)&sm.os[row][col];
            if (col < 64) *(f16x8*)(Qh + grow * 64 + col)        = v;
            else          *(f16x8*)(Kh + grow * 64 + (col - 64)) = v;
        }
    }
}

// ---------------------------------------------------------------------------
// Flash attention v6 = v3 (proven 126.0) with NSPLIT 4->8: grid 1024 -> 4
// blocks/CU (regs ~124/wave, LDS 4x37.4KB=149.5KB <= 160KB). The round-5
// fused-combine fence experiment is reverted (device-scope __threadfence on
// CDNA4 = L2 writeback per block = catastrophic serialization; measured
// attn 109us @ 3% MfmaUtil).
// 32x32x16 MFMA, swapped QK^T, in-register P via cvt_pkrtz+permlane32_swap,
// fdot2 row-sums, 128-row q-tiles, double-buffered K staging, one barrier
// per 64-row k-tile, balanced (31-q, q) block pairing.
// ---------------------------------------------------------------------------
__global__ __launch_bounds__(256, 4) void attn_kernel(const f16* __restrict__ Qh,
                                                      const f16* __restrict__ Kh,
                                                      float* __restrict__ OutP0,
                                                      f16* __restrict__ P123,
                                                      float* __restrict__ Ml) {
    __shared__ __align__(16) f16 Kr[2][64][72];   // 18 KB x2 (double-buffered)
    __shared__ __align__(16) f16 Kt[2][64][72];   // K transposed (V side)

    const int tid  = threadIdx.x;
    const int w    = tid >> 6;
    const int lane = tid & 63;
    const int l31  = lane & 31;
    const int hi   = lane >> 5;

    const int bid  = blockIdx.x;
    const int b    = bid & 3;
    const int half = (bid >> 2) & 7;              // 0..7 split-K slice
    const int qraw = bid >> 5;                    // 0..31
    const int qt   = (qraw < 16) ? (31 - qraw) : (qraw - 16);
    const int q0i  = qt * 128;
    const long q0  = (long)q0i;
    const int jmax = 2 * qt + 1;                  // last 64-row k-tile index

    const f16* Qb = Qh + (long)b * S_LEN * 64;
    const f16* Kb = Kh + (long)b * S_LEN * 64;

    // Q as QK B-frags: lane (col=q=l31, hi) holds Q[q][kf*16 + hi*8 + j]
    f16x8 Bq[4];
#pragma unroll
    for (int kf = 0; kf < 4; kf++)
        Bq[kf] = *(const f16x8*)(Qb + (q0 + w * 32 + l31) * 64 + kf * 16 + hi * 8);

    f32x16 O0 = {}, O1 = {};
    float Lc[4] = {0.f, 0.f, 0.f, 0.f};

    f16x8 pre[2];
    if (half <= jmax) {
#pragma unroll
        for (int it = 0; it < 2; it++)
            pre[it] = *(const f16x8*)(Kb + ((long)half * 64 + lane) * 64 + (w + it * 4) * 8);
    }

    int buf = 0;
    for (int j = half; j <= jmax; j += NSPLIT) {
        // stage current tile into buf (other buffer may still be read by
        // waves before the barrier -> safe)
#pragma unroll
        for (int it = 0; it < 2; it++) {
            int sg = w + it * 4;
            *(f16x8*)&Kr[buf][lane][sg * 8] = pre[it];
#pragma unroll
            for (int i = 0; i < 8; i++) Kt[buf][sg * 8 + i][lane] = pre[it][i];
        }
        if (j + NSPLIT <= jmax) {
#pragma unroll
            for (int it = 0; it < 2; it++)
                pre[it] = *(const f16x8*)(Kb + ((long)(j + NSPLIT) * 64 + lane) * 64 + (w + it * 4) * 8);
        }
        __syncthreads();   // the ONLY barrier per k-tile

        const int od = j * 64 - q0i;              // k-tile offset rel. q-tile
        const bool alive = (od <= w * 32 + 31);   // any unmasked k for wave?
        if (alive) {
            // ---- QK^T swapped: Sc[kb] = K[kb]*Q^T  (C: row=k, col=q) ----
            f32x16 Sc0 = {}, Sc1 = {};
            __builtin_amdgcn_s_setprio(1);
#pragma unroll
            for (int kf = 0; kf < 4; kf++) {
                f16x8 a0 = *(const f16x8*)&Kr[buf][l31][kf * 16 + hi * 8];
                f16x8 a1 = *(const f16x8*)&Kr[buf][32 + l31][kf * 16 + hi * 8];
                Sc0 = __builtin_amdgcn_mfma_f32_32x32x16_f16(a0, Bq[kf], Sc0, 0, 0, 0);
                Sc1 = __builtin_amdgcn_mfma_f32_32x32x16_f16(a1, Bq[kf], Sc1, 0, 0, 0);
            }
            __builtin_amdgcn_s_setprio(0);

            // causal mask: k_g = od + kb*32 + rc + 4hi  vs  q_g = w*32 + l31
            if (od + 63 > w * 32) {
                const int thr = w * 32 + l31 - od - 4 * hi;
#pragma unroll
                for (int r = 0; r < 16; r++) {
                    const int rc = (r & 3) + 8 * (r >> 2);
                    if (rc > thr)      Sc0[r] = -1e30f;
                    if (rc + 32 > thr) Sc1[r] = -1e30f;
                }
            }

            // ---- fixed-shift softmax numerator, in-register ----
            f32x16 pe0, pe1;
#pragma unroll
            for (int r = 0; r < 16; r++) {
                pe0[r] = exp2g(Sc0[r] - SMAX);
                pe1[r] = exp2g(Sc1[r] - SMAX);
            }

            // pack to f16 pairs: C[u][cp] = pkrtz(pe[u>>2][4(u&3)+2cp], +1)
            unsigned Cw[8][2];
#pragma unroll
            for (int u = 0; u < 8; u++) {
#pragma unroll
                for (int cp = 0; cp < 2; cp++) {
                    const int e = 4 * (u & 3) + 2 * cp;
                    h2 t = (u < 4) ? __builtin_amdgcn_cvt_pkrtz(pe0[e], pe0[e + 1])
                                   : __builtin_amdgcn_cvt_pkrtz(pe1[e], pe1[e + 1]);
                    Cw[u][cp] = __builtin_bit_cast(unsigned, t);
                }
            }

            // row-sum L from the SAME f16-rounded P (consistent with PV)
            h2 one2;
            one2[0] = (__fp16)1.f;
            one2[1] = (__fp16)1.f;
#pragma unroll
            for (int u = 0; u < 8; u++)
#pragma unroll
                for (int cp = 0; cp < 2; cp++) {
                    const int c = (u & 1) * 2 + cp;
                    Lc[c] = __builtin_amdgcn_fdot2(__builtin_bit_cast(h2, Cw[u][cp]),
                                                   one2, Lc[c], false);
                }

            // redistribute into PV A-frags: one swap fills two words
            f16x8 pa[4];
#pragma unroll
            for (int kc = 0; kc < 4; kc++) {
                u32x2 s0 = __builtin_amdgcn_permlane32_swap(Cw[2 * kc][0], Cw[2 * kc + 1][0], false, false);
                u32x2 s1 = __builtin_amdgcn_permlane32_swap(Cw[2 * kc][1], Cw[2 * kc + 1][1], false, false);
                union { unsigned uw[4]; f16x8 v; } pw;
                pw.uw[0] = s0.x; pw.uw[1] = s1.x; pw.uw[2] = s0.y; pw.uw[3] = s1.y;
                pa[kc] = pw.v;
            }

            // ---- PV: O[nb] += P * V  (V = K; B-frag from Kt) ----
            __builtin_amdgcn_s_setprio(1);
#pragma unroll
            for (int kc = 0; kc < 4; kc++) {
                f16x8 v0 = *(const f16x8*)&Kt[buf][l31][kc * 16 + hi * 8];
                f16x8 v1 = *(const f16x8*)&Kt[buf][32 + l31][kc * 16 + hi * 8];
                O0 = __builtin_amdgcn_mfma_f32_32x32x16_f16(pa[kc], v0, O0, 0, 0, 0);
                O1 = __builtin_amdgcn_mfma_f32_32x32x16_f16(pa[kc], v1, O1, 0, 0, 0);
            }
            __builtin_amdgcn_s_setprio(0);
        }
        buf ^= 1;
    }

    // finish L: each lane has half the k's for its q; partner lane^32 has rest
    float Lt = Lc[0] + Lc[1] + Lc[2] + Lc[3];
    Lt += __shfl_xor(Lt, 32, 64);

    // write partials. O C-layout: col = nb*32 + l31, row q = rc + 4hi.
    const long growbase = (long)b * S_LEN + q0;
#pragma unroll
    for (int r = 0; r < 16; r++) {
        const int rc = (r & 3) + 8 * (r >> 2);
        long grow = growbase + w * 32 + rc + 4 * hi;
        if (half == 0) {
            OutP0[grow * 64 + l31]      = O0[r];
            OutP0[grow * 64 + 32 + l31] = O1[r];
        } else {
            f16* dst = P123 + (long)(half - 1) * NROWS * 64;
            dst[grow * 64 + l31]      = (f16)O0[r];
            dst[grow * 64 + 32 + l31] = (f16)O1[r];
        }
    }
    if (hi == 0) Ml[(long)half * NROWS + growbase + w * 32 + l31] = Lt;
}

// ---------------------------------------------------------------------------
// Combine: O = sum_h O_h / sum_h l_h  (all halves share the same fixed shift)
// ---------------------------------------------------------------------------
__global__ __launch_bounds__(256) void combine_kernel(float* __restrict__ Out,
                                                      const f16* __restrict__ P123,
                                                      const float* __restrict__ Ml) {
    int gid = blockIdx.x * 256 + threadIdx.x;          // 16384 rows * 16 col-groups
    long row = gid >> 4;
    int c0 = (gid & 15) * 4;
    float lt = 0.f;
#pragma unroll
    for (int h = 0; h < NSPLIT; h++) lt += Ml[(long)h * NROWS + row];
    float inv = 1.0f / lt;

    float* p = Out + row * 64 + c0;
    float4 res = *(const float4*)p;
#pragma unroll
    for (int h = 1; h < NSPLIT; h++) {
        f16x4 oh = *(const f16x4*)(P123 + (long)(h - 1) * NROWS * 64 + row * 64 + c0);
        res.x += (float)oh[0];
        res.y += (float)oh[1];
        res.z += (float)oh[2];
        res.w += (float)oh[3];
    }
    *(float4*)p = make_float4(res.x * inv, res.y * inv, res.z * inv, res.w * inv);
}

// ---------------------------------------------------------------------------
extern "C" void kernel_launch(void* const* d_in, const int* in_sizes, int n_in,
                              void* d_out, int out_size, void* d_ws, size_t ws_size,
                              hipStream_t stream) {
    const float* x  = (const float*)d_in[0];
    const float* Wq = (const float*)d_in[1];
    const float* Wk = (const float*)d_in[2];
    // d_in[3] (Wv) unused: reference computes V with Wk.
    float* out = (float*)d_out;

    // ws layout (~19 MB total)
    f16* Qh    = (f16*)d_ws;                           // 2 MB
    f16* Kh    = Qh + (long)NROWS * D_DIM;             // 2 MB
    f16* Bp    = Kh + (long)NROWS * D_DIM;             // 0.25 MB (packed W frags)
    f16* P123  = Bp + (long)128 * E_DIM;               // 14 MB (7 partials, f16)
    float* Ml  = (float*)(P123 + (long)(NSPLIT - 1) * NROWS * D_DIM); // 0.5 MB

    wpack_kernel<<<dim3(64), dim3(256), 0, stream>>>(Wq, Wk, Bp);
    proj_kernel<<<dim3(NROWS / 32), dim3(256), 0, stream>>>(x, Bp, Qh, Kh);
    attn_kernel<<<dim3(32 * NSPLIT * B_SZ), dim3(256), 0, stream>>>(Qh, Kh, out, P123, Ml);
    combine_kernel<<<dim3(NROWS * 16 / 256), dim3(256), 0, stream>>>(out, P123, Ml);
}